// Round 4
// baseline (586.339 us; speedup 1.0000x reference)
//
#include <hip/hip_runtime.h>

// CausalSelfAttention: B=2, S=2048, H=2048, NH=16, HD=128.
// R4 KEY FIX: inputs/outputs are FLOAT32 (per reference setup_inputs), not bf16.
//   R2==R3 bit-identical garbage proved compute was deterministic+consistent and
//   the bug was interface dtype misread. Convert f32->bf16 once, run bf16 MFMA
//   pipeline (m97-pattern GEMMs + flash attention), write f32 output.

using bf16x8 = __attribute__((ext_vector_type(8))) short;
using f32x4  = __attribute__((ext_vector_type(4))) float;

#define S_LEN 2048
#define NHEAD 16
#define HDIM  128
#define HID   2048

__device__ __forceinline__ unsigned short f2bf(float f) {
    unsigned int u = __float_as_uint(f);
    u += 0x7fffu + ((u >> 16) & 1u);   // round-to-nearest-even
    return (unsigned short)(u >> 16);
}
__device__ __forceinline__ void gl2lds16(const void* g, void* l) {
    // async global->LDS, 16B per lane; LDS dest = wave-uniform base + lane*16
    __builtin_amdgcn_global_load_lds(
        (const __attribute__((address_space(1))) void*)g,
        (__attribute__((address_space(3))) void*)l, 16, 0, 0);
}

// ---------------------------------------------------------------- convert x: f32 -> bf16
__global__ void convert_x(const float* __restrict__ x, unsigned short* __restrict__ xb) {
    int i = (blockIdx.x * 256 + threadIdx.x) * 4;
    float4 v = *(const float4*)(x + i);
    ushort4 o;
    o.x = f2bf(v.x); o.y = f2bf(v.y); o.z = f2bf(v.z); o.w = f2bf(v.w);
    *(ushort4*)(xb + i) = o;
}

// ------------------------------------------------- convert+transpose weights: f32 -> bf16^T
// wT[n][k] = bf16(w[k][n]), 2048x2048, 64x64 tiles.
__global__ void convert_wt(const float* __restrict__ w0, const float* __restrict__ w1,
                           const float* __restrict__ w2, const float* __restrict__ w3,
                           unsigned short* __restrict__ t0, unsigned short* __restrict__ t1,
                           unsigned short* __restrict__ t2, unsigned short* __restrict__ t3) {
    __shared__ float tile[64][65];
    int z = blockIdx.z;
    const float* src = (z == 0) ? w0 : (z == 1) ? w1 : (z == 2) ? w2 : w3;
    unsigned short* dst = (z == 0) ? t0 : (z == 1) ? t1 : (z == 2) ? t2 : t3;
    int r0 = blockIdx.y * 64, c0 = blockIdx.x * 64;
    int t = threadIdx.x;
    for (int i = t; i < 64 * 64; i += 256) {
        int r = i >> 6, c = i & 63;
        tile[r][c] = src[(size_t)(r0 + r) * HID + c0 + c];
    }
    __syncthreads();
    for (int i = t; i < 64 * 64; i += 256) {
        int r = i & 63, c = i >> 6;                 // r fastest -> coalesced store
        dst[(size_t)(c0 + c) * HID + r0 + r] = f2bf(tile[r][c]);
    }
}

// ---------------------------------------------------------------- GEMM (m97 pattern)
// C[M=4096][N=2048] = A[M][K=2048] @ Bt[N][K]^T + bias[N]; A,Bt bf16, bias f32, fp32 acc.
// MODE 0: write f32 row-major [M][N] to Cf (out-proj -> d_out)
// MODE 1: write bf16 head-split C[((b*16+h)*2048+s)*128+d]; blockIdx.z picks q/k/v
template <int MODE>
__launch_bounds__(256, 2)
__global__ void gemm_bt(const unsigned short* __restrict__ A,
                        const unsigned short* __restrict__ Bt0,
                        const unsigned short* __restrict__ Bt1,
                        const unsigned short* __restrict__ Bt2,
                        const float* __restrict__ bias0,
                        const float* __restrict__ bias1,
                        const float* __restrict__ bias2,
                        unsigned short* __restrict__ C0,
                        unsigned short* __restrict__ C1,
                        unsigned short* __restrict__ C2,
                        float* __restrict__ Cf) {
    __shared__ __align__(16) unsigned short As[128 * 32];
    __shared__ __align__(16) unsigned short Bs[128 * 32];

    const unsigned short* Bt = Bt0;
    const float* bias = bias0;
    unsigned short* C = C0;
    if (MODE == 1) {
        int z = blockIdx.z;
        if (z == 1) { Bt = Bt1; bias = bias1; C = C1; }
        else if (z == 2) { Bt = Bt2; bias = bias2; C = C2; }
    }

    const int K = HID;
    int m0 = blockIdx.y * 128;
    int n0 = blockIdx.x * 128;
    int tid = threadIdx.x;
    int lane = tid & 63;
    int w = tid >> 6;
    int wr = w >> 1, wc = w & 1;       // 2x2 waves, each 64x64
    int l15 = lane & 15;
    int quad = lane >> 4;

    f32x4 acc[4][4];
#pragma unroll
    for (int i = 0; i < 4; ++i)
#pragma unroll
        for (int j = 0; j < 4; ++j) acc[i][j] = (f32x4){0.f, 0.f, 0.f, 0.f};

    // staging: wave w covers rows [w*16, w*16+16) and +64; 8 cols per lane
    int srow = w * 16 + (lane >> 2);
    int scol = (lane & 3) * 8;
    const unsigned short* gA = A + (size_t)(m0 + srow) * K + scol;
    const unsigned short* gB = Bt + (size_t)(n0 + srow) * K + scol;
    unsigned short* lA = &As[w * 512];
    unsigned short* lB = &Bs[w * 512];

    for (int k0 = 0; k0 < K; k0 += 32) {
        gl2lds16(gA + k0,                  lA);
        gl2lds16(gA + (size_t)64 * K + k0, lA + 2048);
        gl2lds16(gB + k0,                  lB);
        gl2lds16(gB + (size_t)64 * K + k0, lB + 2048);
        __syncthreads();   // compiler drains vmcnt before s_barrier

        bf16x8 av[4], bv[4];
        int q8 = quad * 8;
#pragma unroll
        for (int i = 0; i < 4; ++i) av[i] = *(const bf16x8*)&As[(wr * 64 + i * 16 + l15) * 32 + q8];
#pragma unroll
        for (int j = 0; j < 4; ++j) bv[j] = *(const bf16x8*)&Bs[(wc * 64 + j * 16 + l15) * 32 + q8];
#pragma unroll
        for (int i = 0; i < 4; ++i)
#pragma unroll
            for (int j = 0; j < 4; ++j)
                acc[i][j] = __builtin_amdgcn_mfma_f32_16x16x32_bf16(av[i], bv[j], acc[i][j], 0, 0, 0);
        __syncthreads();
    }

    // epilogue: C/D layout col=lane&15, row=quad*4+reg
#pragma unroll
    for (int j = 0; j < 4; ++j) {
        int n = n0 + wc * 64 + j * 16 + l15;
        float bn = bias[n];
#pragma unroll
        for (int i = 0; i < 4; ++i) {
#pragma unroll
            for (int reg = 0; reg < 4; ++reg) {
                int m = m0 + wr * 64 + i * 16 + quad * 4 + reg;
                float v = acc[i][j][reg] + bn;
                if (MODE == 0) {
                    Cf[(size_t)m * HID + n] = v;
                } else {
                    int b = m >> 11, s = m & 2047, h = n >> 7, d = n & 127;
                    C[(size_t)(((b << 4) + h) * S_LEN + s) * HDIM + d] = f2bf(v);
                }
            }
        }
    }
}

// ---------------------------------------------------------------- flash attention
// One block = (b, h, 128 Q-rows). 4 waves; wave owns 32 Q-rows. 64-key tiles.
// Firewalls retained (inert when numerics sane): mask -3e4, score clamp, 1/l guard,
// output clamp — keep failure signatures diagnostic.
__launch_bounds__(256, 2)
__global__ void attn_kernel(const unsigned short* __restrict__ Qg,
                            const unsigned short* __restrict__ Kg,
                            const unsigned short* __restrict__ Vg,
                            unsigned short* __restrict__ O) {
    __shared__ __align__(16) unsigned short Ks[64 * 136];   // [key][hd], +8 pad
    __shared__ __align__(16) unsigned short Vt[128 * 72];   // [hd][key], +8 pad
    __shared__ __align__(16) unsigned short Ps[128 * 72];   // [qrow][key], +8 pad

    int qt = blockIdx.x;          // 0..15
    int h  = blockIdx.y;
    int b  = blockIdx.z;
    int bh = b * NHEAD + h;

    int tid = threadIdx.x, lane = tid & 63, w = tid >> 6;
    int l15 = lane & 15, quad = lane >> 4;

    const unsigned short* Qb = Qg + (size_t)bh * S_LEN * HDIM;
    const unsigned short* Kb = Kg + (size_t)bh * S_LEN * HDIM;
    const unsigned short* Vb = Vg + (size_t)bh * S_LEN * HDIM;

    // Q fragments straight from global (A-layout: m=lane&15, k=quad*8+j)
    bf16x8 qf[2][4];
    int qrow0 = qt * 128 + w * 32;
#pragma unroll
    for (int r = 0; r < 2; ++r)
#pragma unroll
        for (int kk = 0; kk < 4; ++kk)
            qf[r][kk] = *(const bf16x8*)&Qb[(size_t)(qrow0 + r * 16 + l15) * HDIM + kk * 32 + quad * 8];

    f32x4 o_acc[2][8];
#pragma unroll
    for (int r = 0; r < 2; ++r)
#pragma unroll
        for (int c = 0; c < 8; ++c) o_acc[r][c] = (f32x4){0.f, 0.f, 0.f, 0.f};
    float m_st[2][4], l_st[2][4];
#pragma unroll
    for (int r = 0; r < 2; ++r)
#pragma unroll
        for (int g = 0; g < 4; ++g) { m_st[r][g] = -30000.f; l_st[r][g] = 0.f; }

    const float scale = 0.08838834764831845f;  // 1/sqrt(128)

    int trow = tid >> 4;           // 0..15
    int tcol = (tid & 15) * 8;     // 0..120

    int nkt = 2 * (qt + 1);
    for (int kt = 0; kt < nkt; ++kt) {
        // ---- stage K tile [64][128] and V tile transposed [128][64]
#pragma unroll
        for (int p = 0; p < 4; ++p) {
            int key = p * 16 + trow;
            bf16x8 kv = *(const bf16x8*)&Kb[(size_t)(kt * 64 + key) * HDIM + tcol];
            *(bf16x8*)&Ks[key * 136 + tcol] = kv;
            bf16x8 vv = *(const bf16x8*)&Vb[(size_t)(kt * 64 + key) * HDIM + tcol];
#pragma unroll
            for (int j = 0; j < 8; ++j)
                Vt[(tcol + j) * 72 + key] = (unsigned short)vv[j];
        }
        __syncthreads();

        // ---- scores: S = Q K^T  (2 r-tiles x 4 c-tiles)
        f32x4 sf[2][4];
#pragma unroll
        for (int c = 0; c < 4; ++c) {
            bf16x8 kb[4];
#pragma unroll
            for (int kk = 0; kk < 4; ++kk)
                kb[kk] = *(const bf16x8*)&Ks[(c * 16 + l15) * 136 + kk * 32 + quad * 8];
#pragma unroll
            for (int r = 0; r < 2; ++r) {
                f32x4 t = (f32x4){0.f, 0.f, 0.f, 0.f};
#pragma unroll
                for (int kk = 0; kk < 4; ++kk)
                    t = __builtin_amdgcn_mfma_f32_16x16x32_bf16(qf[r][kk], kb[kk], t, 0, 0, 0);
                sf[r][c] = t;
            }
        }

        // ---- scale + causal mask + NaN firewall
#pragma unroll
        for (int r = 0; r < 2; ++r)
#pragma unroll
            for (int c = 0; c < 4; ++c)
#pragma unroll
                for (int reg = 0; reg < 4; ++reg) {
                    int qrow = qt * 128 + w * 32 + r * 16 + quad * 4 + reg;
                    int key  = kt * 64 + c * 16 + l15;
                    float v = fminf(fmaxf(sf[r][c][reg] * scale, -30000.f), 30000.f);
                    sf[r][c][reg] = (key <= qrow) ? v : -30000.f;
                }

        // ---- online softmax (row state per (r,reg); reduce across quad's 16 lanes)
        float alpha[2][4];
#pragma unroll
        for (int r = 0; r < 2; ++r)
#pragma unroll
            for (int reg = 0; reg < 4; ++reg) {
                float mloc = fmaxf(fmaxf(sf[r][0][reg], sf[r][1][reg]),
                                   fmaxf(sf[r][2][reg], sf[r][3][reg]));
#pragma unroll
                for (int off = 8; off >= 1; off >>= 1)
                    mloc = fmaxf(mloc, __shfl_xor(mloc, off, 64));
                float mold = m_st[r][reg];
                float mnew = fmaxf(mold, mloc);
                float al = __expf(mold - mnew);
                float ps = 0.f;
#pragma unroll
                for (int c = 0; c < 4; ++c) {
                    float p = __expf(sf[r][c][reg] - mnew);
                    sf[r][c][reg] = p;
                    ps += p;
                }
#pragma unroll
                for (int off = 8; off >= 1; off >>= 1)
                    ps += __shfl_xor(ps, off, 64);
                m_st[r][reg] = mnew;
                l_st[r][reg] = l_st[r][reg] * al + ps;
                alpha[r][reg] = al;
            }
#pragma unroll
        for (int r = 0; r < 2; ++r)
#pragma unroll
            for (int c = 0; c < 8; ++c)
#pragma unroll
                for (int reg = 0; reg < 4; ++reg)
                    o_acc[r][c][reg] *= alpha[r][reg];

        // ---- P: C-layout -> LDS (bf16) -> A-layout
#pragma unroll
        for (int r = 0; r < 2; ++r)
#pragma unroll
            for (int c = 0; c < 4; ++c)
#pragma unroll
                for (int reg = 0; reg < 4; ++reg)
                    Ps[(w * 32 + r * 16 + quad * 4 + reg) * 72 + c * 16 + l15] =
                        f2bf(sf[r][c][reg]);
        __syncthreads();   // order P writes vs reads (and Vt visibility)

        // ---- O += P V
        bf16x8 pf[2][2];
#pragma unroll
        for (int r = 0; r < 2; ++r)
#pragma unroll
            for (int kk = 0; kk < 2; ++kk)
                pf[r][kk] = *(const bf16x8*)&Ps[(w * 32 + r * 16 + l15) * 72 + kk * 32 + quad * 8];
#pragma unroll
        for (int ct = 0; ct < 8; ++ct) {
            bf16x8 vbf[2];
#pragma unroll
            for (int kk = 0; kk < 2; ++kk)
                vbf[kk] = *(const bf16x8*)&Vt[(ct * 16 + l15) * 72 + kk * 32 + quad * 8];
#pragma unroll
            for (int r = 0; r < 2; ++r) {
                f32x4 t = o_acc[r][ct];
#pragma unroll
                for (int kk = 0; kk < 2; ++kk)
                    t = __builtin_amdgcn_mfma_f32_16x16x32_bf16(pf[r][kk], vbf[kk], t, 0, 0, 0);
                o_acc[r][ct] = t;
            }
        }
        __syncthreads();   // protect Ks/Vt restage next iter
    }

    // ---- epilogue: O / l, write bf16 head-merged [B][S][H]
#pragma unroll
    for (int r = 0; r < 2; ++r)
#pragma unroll
        for (int reg = 0; reg < 4; ++reg) {
            float inv = 1.f / fmaxf(l_st[r][reg], 1e-20f);
            int srow = qt * 128 + w * 32 + r * 16 + quad * 4 + reg;
            unsigned short* op = O + (size_t)(b * S_LEN + srow) * HID + h * HDIM;
#pragma unroll
            for (int ct = 0; ct < 8; ++ct) {
                float val = o_acc[r][ct][reg] * inv;
                val = fminf(fmaxf(val, -1e4f), 1e4f);   // sanitizes NaN -> -1e4
                op[ct * 16 + l15] = f2bf(val);
            }
        }
}

// ---------------------------------------------------------------- launch
extern "C" void kernel_launch(void* const* d_in, const int* in_sizes, int n_in,
                              void* d_out, int out_size, void* d_ws, size_t ws_size,
                              hipStream_t stream) {
    (void)in_sizes; (void)n_in; (void)out_size; (void)ws_size;
    // ALL inputs are float32 (reference setup_inputs dtype).
    const float* x  = (const float*)d_in[0];
    // d_in[1] = additive causal mask; exactly tril -> applied analytically
    const float* wq = (const float*)d_in[2];
    const float* bq = (const float*)d_in[3];
    const float* wk = (const float*)d_in[4];
    const float* bk = (const float*)d_in[5];
    const float* wv = (const float*)d_in[6];
    const float* bv = (const float*)d_in[7];
    const float* wo = (const float*)d_in[8];
    const float* bo = (const float*)d_in[9];
    float* out = (float*)d_out;   // float32 output [B][S][H]

    // workspace carve (bf16 elements, 4M els = 8 MB). Total 48M els = 96 MB.
    // Ab aliases xb (xb dead after QKV gemm; attn runs strictly after on same stream).
    unsigned short* ws = (unsigned short*)d_ws;
    const size_t WSZ = 4194304;
    unsigned short* wqT = ws;                // [0, 4M)
    unsigned short* wkT = ws + WSZ;          // [4M, 8M)
    unsigned short* wvT = ws + 2 * WSZ;      // [8M, 12M)
    unsigned short* woT = ws + 3 * WSZ;      // [12M, 16M)
    unsigned short* xb  = ws + 4 * WSZ;      // [16M, 24M)
    unsigned short* Ab  = ws + 4 * WSZ;      // aliases xb
    unsigned short* Qb  = ws + 6 * WSZ;      // [24M, 32M)
    unsigned short* Kb  = ws + 8 * WSZ;      // [32M, 40M)
    unsigned short* Vb  = ws + 10 * WSZ;     // [40M, 48M)

    convert_x<<<dim3(8192), 256, 0, stream>>>(x, xb);
    convert_wt<<<dim3(32, 32, 4), 256, 0, stream>>>(wq, wk, wv, wo, wqT, wkT, wvT, woT);
    gemm_bt<1><<<dim3(16, 32, 3), 256, 0, stream>>>(xb, wqT, wkT, wvT, bq, bk, bv,
                                                    Qb, Kb, Vb, nullptr);
    attn_kernel<<<dim3(16, 16, 2), 256, 0, stream>>>(Qb, Kb, Vb, Ab);
    gemm_bt<0><<<dim3(16, 32, 1), 256, 0, stream>>>(Ab, woT, nullptr, nullptr,
                                                    bo, nullptr, nullptr,
                                                    nullptr, nullptr, nullptr, out);
}